// Round 7
// baseline (265.075 us; speedup 1.0000x reference)
//
#include <hip/hip_runtime.h>
#include <hip/hip_bf16.h>

typedef __attribute__((ext_vector_type(8))) short short8;
typedef __attribute__((ext_vector_type(4))) float f32x4;

// ws layout (bytes)
#define WFT_OFF 0          // bf16 WfTr[16][256][32]  = 262144 B (k-chunk-major)
#define HB_OFF  262144     // f32[32*256]             =  32768 B
#define SC_OFF  294912     // f32[131072] scores      = 524288 B
#define ST_OFF  819200     // f32[2048*2] m,l         =  16384 B
#define CP_OFF  835584     // f32[2048*512] ctx part  = 4194304 B (total ~5 MB)

__device__ __forceinline__ float bf2f(unsigned short h) {
    unsigned u = ((unsigned)h) << 16;
    return __builtin_bit_cast(float, u);
}
__device__ __forceinline__ unsigned pack_bf16(float a, float b) {
    unsigned short sa = __builtin_bit_cast(unsigned short, __float2bfloat16(a));
    unsigned short sb = __builtin_bit_cast(unsigned short, __float2bfloat16(b));
    return (unsigned)sa | ((unsigned)sb << 16);
}
__device__ __forceinline__ short8 cvt8(float4 a, float4 b) {
    union { unsigned u[4]; short8 s; } r;
    r.u[0] = pack_bf16(a.x, a.y); r.u[1] = pack_bf16(a.z, a.w);
    r.u[2] = pack_bf16(b.x, b.y); r.u[3] = pack_bf16(b.z, b.w);
    return r.s;
}
__device__ __forceinline__ float fast_tanh(float x) {
    float e2 = __expf(2.0f * x);
    return 1.0f - 2.0f / (e2 + 1.0f);
}
__device__ __forceinline__ void lds_barrier() {
    asm volatile("s_waitcnt lgkmcnt(0)" ::: "memory");
    __builtin_amdgcn_s_barrier();
}

// ---- Wf (512x256 f32) -> WfTr[ks][col][kk] bf16 (k-chunk-major for frag loads) ----
// elem (col a, k d) stored at ks*8192 + a*32 + (d&31), ks = d>>5.
__global__ void wft_kernel(const float* __restrict__ Wf, unsigned short* __restrict__ WfTr) {
    __shared__ unsigned short tl[64 * 80];
    const int t = threadIdx.x;
    const int tk = blockIdx.x >> 2, ta = blockIdx.x & 3;
    const int d0 = tk * 64, a0 = ta * 64;
#pragma unroll
    for (int i = 0; i < 16; ++i) {
        int flat = t + 256 * i;
        int dl = flat >> 6, al = flat & 63;
        tl[al * 80 + dl] = __builtin_bit_cast(unsigned short,
                               __float2bfloat16(Wf[(d0 + dl) * 256 + a0 + al]));
    }
    __syncthreads();
#pragma unroll
    for (int i = 0; i < 2; ++i) {
        int u = t + 256 * i;
        int al = u >> 3, q = u & 7;
        int k = d0 + q * 8;
        int ks = k >> 5, kk = k & 31;
        *(uint4*)(&WfTr[(size_t)ks * 8192 + (a0 + al) * 32 + kk]) =
            *(const uint4*)(&tl[al * 80 + q * 8]);
    }
}

// ---- hb[b][a] = hidden[b]·Wh[:,a] + bh[a] + bf[a] ----
__global__ void hb_kernel(const float* __restrict__ hidden, const float* __restrict__ Wh,
                          const float* __restrict__ bh, const float* __restrict__ bfv,
                          float* __restrict__ hb) {
    const int b = blockIdx.x, a = threadIdx.x;
    float acc = bh[a] + bfv[a];
    const float* hrow = hidden + b * 512;
#pragma unroll 8
    for (int d = 0; d < 512; ++d)
        acc += hrow[d] * Wh[d * 256 + a];
    hb[b * 256 + a] = acc;
}

// ---- S: barrier-free GEMM — A fragments DIRECT from global, no LDS staging ----
// 2048 tiles x 64 rows, 512 thr. 8 waves = 4 row-groups x 2 col-halves
// (16 rows x 128 cols each). Per ks: 8 B-frags (L2) + 1 A-frag (HBM) with
// rolling 1-ks prefetch; waves stream independently, no phase convoy.
__launch_bounds__(512, 4)
__global__ void scores_kernel(const float* __restrict__ feats,
                              const unsigned short* __restrict__ WfTr,
                              const float* __restrict__ hbg,
                              const float* __restrict__ Ws,
                              float* __restrict__ scores,
                              float* __restrict__ stats) {
    __shared__ float wpart[128];

    const int t = threadIdx.x;
    const int tile = blockIdx.x;
    const int b = tile >> 6;
    const int row0 = tile * 64;
    const int lane = t & 63, w = t >> 6;
    const int wr = w & 3, wcg = w >> 2;         // row-group, col-half
    const int lr = lane & 15, lg = lane >> 4;

    // A: lane loads 8 consecutive f32 of its MFMA-A row per ks
    const float4* ap4 = (const float4*)(feats + (size_t)(row0 + wr * 16 + lr) * 512 + lg * 8);
    // B: frag c at bp[c*64] uint4s within a ks-chunk; ks stride 1024 uint4
    const uint4* bp = (const uint4*)(WfTr + (size_t)(wcg * 128 + lr) * 32 + lg * 8);

    f32x4 acc[8] = {};
    uint4 bq[8];
    short8 af;
    float4 aq0, aq1;

    // prologue: B(0), A(0)->af, A(1) in flight
#pragma unroll
    for (int c = 0; c < 8; ++c) bq[c] = bp[c * 64];
    {
        float4 x0 = ap4[0], x1 = ap4[1];
        af = cvt8(x0, x1);
    }
    aq0 = ap4[8]; aq1 = ap4[9];

#pragma unroll
    for (int ks = 0; ks < 16; ++ks) {
        uint4 bn[8];
        const int kso = (ks + 1) * 1024;
        if (ks < 15) {                          // issue next-ks B group 0
            bn[0] = bp[kso];       bn[1] = bp[kso + 64];
            bn[2] = bp[kso + 128]; bn[3] = bp[kso + 192];
        }
        acc[0] = __builtin_amdgcn_mfma_f32_16x16x32_bf16(af, __builtin_bit_cast(short8, bq[0]), acc[0], 0, 0, 0);
        acc[1] = __builtin_amdgcn_mfma_f32_16x16x32_bf16(af, __builtin_bit_cast(short8, bq[1]), acc[1], 0, 0, 0);
        acc[2] = __builtin_amdgcn_mfma_f32_16x16x32_bf16(af, __builtin_bit_cast(short8, bq[2]), acc[2], 0, 0, 0);
        acc[3] = __builtin_amdgcn_mfma_f32_16x16x32_bf16(af, __builtin_bit_cast(short8, bq[3]), acc[3], 0, 0, 0);
        if (ks < 15) {                          // issue next-ks B group 1 (bq[0..3] now dead)
            bn[4] = bp[kso + 256]; bn[5] = bp[kso + 320];
            bn[6] = bp[kso + 384]; bn[7] = bp[kso + 448];
        }
        short8 afn;
        if (ks < 15) afn = cvt8(aq0, aq1);      // consume A(ks+1)
        if (ks < 14) {                          // issue A(ks+2) — HBM stream stays deep
            aq0 = ap4[(ks + 2) * 8];
            aq1 = ap4[(ks + 2) * 8 + 1];
        }
        acc[4] = __builtin_amdgcn_mfma_f32_16x16x32_bf16(af, __builtin_bit_cast(short8, bq[4]), acc[4], 0, 0, 0);
        acc[5] = __builtin_amdgcn_mfma_f32_16x16x32_bf16(af, __builtin_bit_cast(short8, bq[5]), acc[5], 0, 0, 0);
        acc[6] = __builtin_amdgcn_mfma_f32_16x16x32_bf16(af, __builtin_bit_cast(short8, bq[6]), acc[6], 0, 0, 0);
        acc[7] = __builtin_amdgcn_mfma_f32_16x16x32_bf16(af, __builtin_bit_cast(short8, bq[7]), acc[7], 0, 0, 0);
        if (ks < 15) {
            af = afn;
#pragma unroll
            for (int c = 0; c < 8; ++c) bq[c] = bn[c];
        }
    }

    // epilogue operands (L2-hot, loaded after GEMM regs die)
    float hbv[8], wsv[8];
#pragma unroll
    for (int c = 0; c < 8; ++c) {
        int col = wcg * 128 + c * 16 + lr;
        hbv[c] = hbg[b * 256 + col];
        wsv[c] = Ws[col];
    }

    // scores = sum_a tanh(C + hb[a]) * Ws[a]; C frag: col=lr, row=wr*16+lg*4+r
#pragma unroll
    for (int r = 0; r < 4; ++r) {
        float p = 0.f;
#pragma unroll
        for (int c = 0; c < 8; ++c)
            p += fast_tanh(acc[c][r] + hbv[c]) * wsv[c];
#pragma unroll
        for (int off = 1; off < 16; off <<= 1) p += __shfl_xor(p, off, 64);
        if (lr == 0) wpart[w * 16 + lg * 4 + r] = p;
    }
    lds_barrier();

    // per-tile softmax stats (wave 0); col-halves combine here
    if (t < 64) {
        float s = wpart[t] + wpart[64 + t];
        scores[row0 + t] = s;
        float m = s;
#pragma unroll
        for (int off = 1; off < 64; off <<= 1) m = fmaxf(m, __shfl_xor(m, off, 64));
        float e = __expf(s - m);
        float l = e;
#pragma unroll
        for (int off = 1; off < 64; off <<= 1) l += __shfl_xor(l, off, 64);
        if (t == 0) { stats[tile * 2] = m; stats[tile * 2 + 1] = l; }
    }
}

// ---- C: ctx partials — pure feats stream (proven fast in R6) ----
__launch_bounds__(256, 8)
__global__ void ctx_kernel(const float* __restrict__ feats,
                           const float* __restrict__ scores,
                           const float* __restrict__ stats,
                           float* __restrict__ ctxp) {
    __shared__ float wbuf[64];
    const int tile = blockIdx.x;
    const int row0 = tile * 64;
    const int t = threadIdx.x;

    if (t < 64) wbuf[t] = __expf(scores[row0 + t] - stats[tile * 2]);
    __syncthreads();

    const float* fb = feats + (size_t)row0 * 512 + t * 2;
    float accx = 0.f, accy = 0.f;
    for (int n0 = 0; n0 < 64; n0 += 8) {
        float2 v[8]; float sc[8];
#pragma unroll
        for (int u = 0; u < 8; ++u) {
            sc[u] = wbuf[n0 + u];
            v[u]  = *(const float2*)(fb + (size_t)(n0 + u) * 512);
        }
#pragma unroll
        for (int u = 0; u < 8; ++u) { accx += sc[u] * v[u].x; accy += sc[u] * v[u].y; }
    }
    float2 o; o.x = accx; o.y = accy;
    *(float2*)(ctxp + (size_t)tile * 512 + t * 2) = o;
}

// ---- per-batch: global softmax (64 partials) + alpha + ctx merge ----
__global__ void combine_kernel(const float* __restrict__ scores,
                               const float* __restrict__ stats,
                               const float* __restrict__ ctxp,
                               float* __restrict__ out_ctx,
                               float* __restrict__ out_alpha) {
    __shared__ float scales[64];
    __shared__ float MZ[2];
    const int b = blockIdx.x, t = threadIdx.x;
    if (t < 64) {
        float mk = stats[(b * 64 + t) * 2];
        float lk = stats[(b * 64 + t) * 2 + 1];
        float M = mk;
#pragma unroll
        for (int off = 1; off < 64; off <<= 1) M = fmaxf(M, __shfl_xor(M, off, 64));
        float e = __expf(mk - M);
        float z = lk * e;
#pragma unroll
        for (int off = 1; off < 64; off <<= 1) z += __shfl_xor(z, off, 64);
        scales[t] = e / z;
        if (t == 0) { MZ[0] = M; MZ[1] = z; }
    }
    __syncthreads();
    const float M = MZ[0], invZ = 1.0f / MZ[1];
    const float* sb = scores + b * 4096;
    float* abp = out_alpha + b * 4096;
#pragma unroll
    for (int i = 0; i < 16; ++i) {
        int n = t + 256 * i;
        abp[n] = __expf(sb[n] - M) * invZ;
    }
    const int d0 = t * 2;
    const float* cb = ctxp + (size_t)b * 64 * 512;
    float accx = 0.f, accy = 0.f;
    for (int k0 = 0; k0 < 64; k0 += 8) {
        float2 v[8]; float s[8];
#pragma unroll
        for (int u = 0; u < 8; ++u) {
            s[u] = scales[k0 + u];
            v[u] = *(const float2*)(cb + (size_t)(k0 + u) * 512 + d0);
        }
#pragma unroll
        for (int u = 0; u < 8; ++u) { accx += s[u] * v[u].x; accy += s[u] * v[u].y; }
    }
    float2 o; o.x = accx; o.y = accy;
    *(float2*)(out_ctx + b * 512 + d0) = o;
}

extern "C" void kernel_launch(void* const* d_in, const int* in_sizes, int n_in,
                              void* d_out, int out_size, void* d_ws, size_t ws_size,
                              hipStream_t stream) {
    (void)in_sizes; (void)n_in; (void)out_size; (void)ws_size;
    const float* feats  = (const float*)d_in[0];
    const float* hidden = (const float*)d_in[1];
    const float* Wf     = (const float*)d_in[2];
    const float* bfv    = (const float*)d_in[3];
    const float* Wh     = (const float*)d_in[4];
    const float* bh     = (const float*)d_in[5];
    const float* Ws     = (const float*)d_in[6];
    // d_in[7] (bs) irrelevant: softmax is shift-invariant and scores are not output.

    char* ws = (char*)d_ws;
    unsigned short* WfTr = (unsigned short*)(ws + WFT_OFF);
    float* hb     = (float*)(ws + HB_OFF);
    float* scores = (float*)(ws + SC_OFF);
    float* stats  = (float*)(ws + ST_OFF);
    float* ctxp   = (float*)(ws + CP_OFF);

    float* out_ctx   = (float*)d_out;
    float* out_alpha = out_ctx + 32 * 512;

    hipLaunchKernelGGL(wft_kernel, dim3(32), dim3(256), 0, stream, Wf, WfTr);
    hipLaunchKernelGGL(hb_kernel, dim3(32), dim3(256), 0, stream, hidden, Wh, bh, bfv, hb);
    hipLaunchKernelGGL(scores_kernel, dim3(2048), dim3(512), 0, stream,
                       feats, WfTr, hb, Ws, scores, stats);
    hipLaunchKernelGGL(ctx_kernel, dim3(2048), dim3(256), 0, stream,
                       feats, scores, stats, ctxp);
    hipLaunchKernelGGL(combine_kernel, dim3(32), dim3(256), 0, stream,
                       scores, stats, ctxp, out_ctx, out_alpha);
}

// Round 8
// 189.473 us; speedup vs baseline: 1.3990x; 1.3990x over previous
//
#include <hip/hip_runtime.h>
#include <hip/hip_bf16.h>

typedef __attribute__((ext_vector_type(8))) short short8;
typedef __attribute__((ext_vector_type(4))) float f32x4;

// ws layout (bytes)
#define WFT_OFF 0          // bf16 image WfTi[16][256 cols][64 B swz] = 262144 B
#define HB_OFF  262144     // f32[32*256]             =  32768 B
#define SC_OFF  294912     // f32[131072] scores      = 524288 B
#define ST_OFF  819200     // f32[4096*2] m,l         =  32768 B
#define CP_OFF  851968     // f32[4096*512] ctx part  = 8388608 B (total ~9.2 MB)

// scores LDS: Ab [32][1024B] @0 (32 KB), Bw 8 waves x 2 x 2 KB @32768 (32 KB),
//             wpart [8][32] f32 @65536 (1 KB) -> 66560 B => 2 blocks/CU
#define SMEM_S 66560

__device__ __forceinline__ float bf2f(unsigned short h) {
    unsigned u = ((unsigned)h) << 16;
    return __builtin_bit_cast(float, u);
}
__device__ __forceinline__ unsigned pack_bf16(float a, float b) {
    unsigned short sa = __builtin_bit_cast(unsigned short, __float2bfloat16(a));
    unsigned short sb = __builtin_bit_cast(unsigned short, __float2bfloat16(b));
    return (unsigned)sa | ((unsigned)sb << 16);
}
__device__ __forceinline__ float fast_tanh(float x) {
    float e2 = __expf(2.0f * x);
    return 1.0f - 2.0f / (e2 + 1.0f);
}
__device__ __forceinline__ void lds_barrier() {
    asm volatile("s_waitcnt lgkmcnt(0)" ::: "memory");
    __builtin_amdgcn_s_barrier();
}
// async global->LDS, 16 B/lane; LDS dest = wave-uniform base + lane*16
__device__ __forceinline__ void gld_lds16(const char* g, char* l) {
    __builtin_amdgcn_global_load_lds(
        (const __attribute__((address_space(1))) void*)g,
        (__attribute__((address_space(3))) void*)l, 16, 0, 0);
}

// ---- Wf (512x256 f32) -> bf16 image: [ks][col][64B], 16B-block q at
//      byte col*64 + 16*(q ^ ((col>>1)&3)).  gload_lds copies linearly;
//      the swizzled ds_read then lands 2-way-bank (free). ----
__global__ void wft_kernel(const float* __restrict__ Wf, unsigned short* __restrict__ WfTi) {
    __shared__ unsigned short tl[64 * 80];
    const int t = threadIdx.x;
    const int tk = blockIdx.x >> 2, ta = blockIdx.x & 3;
    const int d0 = tk * 64, a0 = ta * 64;
#pragma unroll
    for (int i = 0; i < 16; ++i) {
        int flat = t + 256 * i;
        int dl = flat >> 6, al = flat & 63;
        tl[al * 80 + dl] = __builtin_bit_cast(unsigned short,
                               __float2bfloat16(Wf[(d0 + dl) * 256 + a0 + al]));
    }
    __syncthreads();
    uint4* img = (uint4*)WfTi;
#pragma unroll
    for (int i = 0; i < 2; ++i) {
        int u = t + 256 * i;
        int al = u >> 3, q = u & 7;          // q: which 8-k group within 64
        int a = a0 + al;
        int ks = tk * 2 + (q >> 2);          // k-chunk of 32
        int qq = q & 3;                      // 16B block within chunk
        img[ks * 1024 + a * 4 + (qq ^ ((a >> 1) & 3))] =
            *(const uint4*)(&tl[al * 80 + q * 8]);
    }
}

// ---- hb[b][a] = hidden[b]·Wh[:,a] + bh[a] + bf[a] ----
__global__ void hb_kernel(const float* __restrict__ hidden, const float* __restrict__ Wh,
                          const float* __restrict__ bh, const float* __restrict__ bfv,
                          float* __restrict__ hb) {
    const int b = blockIdx.x, a = threadIdx.x;
    float acc = bh[a] + bfv[a];
    const float* hrow = hidden + b * 512;
#pragma unroll 8
    for (int d = 0; d < 512; ++d)
        acc += hrow[d] * Wh[d * 256 + a];
    hb[b * 256 + a] = acc;
}

// ---- S: 4096 tiles x 32 rows, 512 thr, 8 waves (wave = 32 rows x 32 cols).
// K-loop touches ONLY LDS + MFMA: B streamed by wave-private global_load_lds
// double-buffer (drain vmcnt(0) at top covers B(ks) issued one iter earlier),
// A LDS-resident. Zero barriers in the K-loop. ----
__launch_bounds__(512, 4)
__global__ void scores_kernel(const float* __restrict__ feats,
                              const unsigned short* __restrict__ WfTi,
                              const float* __restrict__ hbg,
                              const float* __restrict__ Ws,
                              float* __restrict__ scores,
                              float* __restrict__ stats) {
    extern __shared__ char smem[];
    char* Ab     = smem;                     // [32][1024 B] bf16, row-XOR swizzled
    char* Bb     = smem + 32768;             // 8 waves x 2 bufs x 2048 B
    float* wpart = (float*)(smem + 65536);   // [8][32]

    const int t = threadIdx.x;
    const int tile = blockIdx.x;
    const int b = tile >> 7;                 // 128 tiles per batch
    const int row0 = tile * 32;
    const int lane = t & 63, w = t >> 6;     // wave w owns cols w*32..+31
    const int lr = lane & 15, lg = lane >> 4;

    char* bw = Bb + w * 4096;                // wave-private B double-buffer
    const char* bimg = (const char*)WfTi + w * 2048 + lane * 16;

    // B(0) issued first (flies under A staging)
    gld_lds16(bimg, bw);
    gld_lds16(bimg + 1024, bw + 1024);

    // stage A tile: feats f32 -> bf16 LDS (32 rows, 16 thr/row, 8 float4 each)
    {
        const int ar = t >> 4, c8 = t & 15;
        const float4* fr = (const float4*)(feats + (size_t)(row0 + ar) * 512);
        char* arow = Ab + ar * 1024;
        const int rsw = (ar & 7) << 4;
#pragma unroll
        for (int i = 0; i < 8; ++i) {
            int f4 = c8 + i * 16;
            float4 v = fr[f4];
            uint2 u;
            u.x = pack_bf16(v.x, v.y);
            u.y = pack_bf16(v.z, v.w);
            *(uint2*)(arow + ((f4 * 8) ^ rsw)) = u;
        }
    }

    // epilogue operands (L2-hot, retire long before use)
    float hbv[2], wsv[2];
#pragma unroll
    for (int j = 0; j < 2; ++j) {
        int col = w * 32 + j * 16 + lr;
        hbv[j] = hbg[b * 256 + col];
        wsv[j] = Ws[col];
    }

    lds_barrier();                           // A visible to all waves (B wave-own)

    f32x4 acc[2][2] = {};
#pragma unroll
    for (int ks = 0; ks < 16; ++ks) {
        // B(ks) resident after this (issued one full iteration ago)
        asm volatile("s_waitcnt vmcnt(0)" ::: "memory");
        char* bcur = bw + (ks & 1) * 2048;
        if (ks < 15) {                       // issue B(ks+1) -> other buffer
            const char* bs = bimg + (ks + 1) * 16384;
            char* bnx = bw + ((ks + 1) & 1) * 2048;
            gld_lds16(bs, bnx);
            gld_lds16(bs + 1024, bnx + 1024);
        }
        short8 af[2], bf[2];
#pragma unroll
        for (int j = 0; j < 2; ++j) {
            int lc = j * 16 + lr;
            bf[j] = *(const short8*)(bcur + lc * 64 + ((lg * 16) ^ (((lc >> 1) & 3) << 4)));
        }
#pragma unroll
        for (int i = 0; i < 2; ++i) {
            int row = i * 16 + lr;
            af[i] = *(const short8*)(Ab + row * 1024 + ((ks * 64 + lg * 16) ^ ((row & 7) << 4)));
        }
#pragma unroll
        for (int i = 0; i < 2; ++i)
#pragma unroll
            for (int j = 0; j < 2; ++j)
                acc[i][j] = __builtin_amdgcn_mfma_f32_16x16x32_bf16(af[i], bf[j], acc[i][j], 0, 0, 0);
    }

    // scores = sum_a tanh(C + hb[a]) * Ws[a]; C frag: col=lr, row=i*16+lg*4+r
#pragma unroll
    for (int i = 0; i < 2; ++i) {
#pragma unroll
        for (int r = 0; r < 4; ++r) {
            float p = fast_tanh(acc[i][0][r] + hbv[0]) * wsv[0]
                    + fast_tanh(acc[i][1][r] + hbv[1]) * wsv[1];
#pragma unroll
            for (int off = 1; off < 16; off <<= 1) p += __shfl_xor(p, off, 64);
            if (lr == 0) wpart[w * 32 + i * 16 + lg * 4 + r] = p;
        }
    }
    lds_barrier();

    // per-tile softmax stats (first 32 lanes)
    if (t < 32) {
        float s = 0.f;
#pragma unroll
        for (int k = 0; k < 8; ++k) s += wpart[k * 32 + t];
        scores[row0 + t] = s;
        float m = s;
#pragma unroll
        for (int off = 1; off < 32; off <<= 1) m = fmaxf(m, __shfl_xor(m, off, 32));
        float e = __expf(s - m);
        float l = e;
#pragma unroll
        for (int off = 1; off < 32; off <<= 1) l += __shfl_xor(l, off, 32);
        if (t == 0) { stats[tile * 2] = m; stats[tile * 2 + 1] = l; }
    }
}

// ---- C: ctx partials over 32-row tiles — pure feats stream (proven fast) ----
__launch_bounds__(256, 8)
__global__ void ctx_kernel(const float* __restrict__ feats,
                           const float* __restrict__ scores,
                           const float* __restrict__ stats,
                           float* __restrict__ ctxp) {
    __shared__ float wbuf[32];
    const int tile = blockIdx.x;
    const int row0 = tile * 32;
    const int t = threadIdx.x;

    if (t < 32) wbuf[t] = __expf(scores[row0 + t] - stats[tile * 2]);
    __syncthreads();

    const float* fb = feats + (size_t)row0 * 512 + t * 2;
    float accx = 0.f, accy = 0.f;
    for (int n0 = 0; n0 < 32; n0 += 8) {
        float2 v[8]; float sc[8];
#pragma unroll
        for (int u = 0; u < 8; ++u) {
            sc[u] = wbuf[n0 + u];
            v[u]  = *(const float2*)(fb + (size_t)(n0 + u) * 512);
        }
#pragma unroll
        for (int u = 0; u < 8; ++u) { accx += sc[u] * v[u].x; accy += sc[u] * v[u].y; }
    }
    float2 o; o.x = accx; o.y = accy;
    *(float2*)(ctxp + (size_t)tile * 512 + t * 2) = o;
}

// ---- per-batch: global softmax over 128 partials + alpha + ctx merge ----
__global__ void combine_kernel(const float* __restrict__ scores,
                               const float* __restrict__ stats,
                               const float* __restrict__ ctxp,
                               float* __restrict__ out_ctx,
                               float* __restrict__ out_alpha) {
    __shared__ float scales[128];
    __shared__ float red[4];
    const int b = blockIdx.x, t = threadIdx.x;
    float mk = -1e30f, lk = 0.f, e = 0.f;
    if (t < 128) {
        mk = stats[(b * 128 + t) * 2];
        lk = stats[(b * 128 + t) * 2 + 1];
    }
    float M = mk;
#pragma unroll
    for (int off = 1; off < 64; off <<= 1) M = fmaxf(M, __shfl_xor(M, off, 64));
    if ((t & 63) == 0) red[t >> 6] = M;
    __syncthreads();
    M = fmaxf(red[0], red[1]);
    if (t < 128) e = __expf(mk - M);
    float z = e * lk;
#pragma unroll
    for (int off = 1; off < 64; off <<= 1) z += __shfl_xor(z, off, 64);
    __syncthreads();
    if ((t & 63) == 0) red[t >> 6] = z;
    __syncthreads();
    const float Z = red[0] + red[1];
    if (t < 128) scales[t] = e / Z;
    __syncthreads();

    const float invZ = 1.0f / Z;
    const float* sb = scores + b * 4096;
    float* abp = out_alpha + b * 4096;
#pragma unroll
    for (int i = 0; i < 16; ++i) {
        int n = t + 256 * i;
        abp[n] = __expf(sb[n] - M) * invZ;
    }
    const int d0 = t * 2;
    const float* cb = ctxp + (size_t)b * 128 * 512;
    float accx = 0.f, accy = 0.f;
    for (int k0 = 0; k0 < 128; k0 += 8) {
        float2 v[8]; float s[8];
#pragma unroll
        for (int u = 0; u < 8; ++u) {
            s[u] = scales[k0 + u];
            v[u] = *(const float2*)(cb + (size_t)(k0 + u) * 512 + d0);
        }
#pragma unroll
        for (int u = 0; u < 8; ++u) { accx += s[u] * v[u].x; accy += s[u] * v[u].y; }
    }
    float2 o; o.x = accx; o.y = accy;
    *(float2*)(out_ctx + b * 512 + d0) = o;
}

extern "C" void kernel_launch(void* const* d_in, const int* in_sizes, int n_in,
                              void* d_out, int out_size, void* d_ws, size_t ws_size,
                              hipStream_t stream) {
    (void)in_sizes; (void)n_in; (void)out_size; (void)ws_size;
    const float* feats  = (const float*)d_in[0];
    const float* hidden = (const float*)d_in[1];
    const float* Wf     = (const float*)d_in[2];
    const float* bfv    = (const float*)d_in[3];
    const float* Wh     = (const float*)d_in[4];
    const float* bh     = (const float*)d_in[5];
    const float* Ws     = (const float*)d_in[6];
    // d_in[7] (bs) irrelevant: softmax is shift-invariant and scores are not output.

    char* ws = (char*)d_ws;
    unsigned short* WfTi = (unsigned short*)(ws + WFT_OFF);
    float* hb     = (float*)(ws + HB_OFF);
    float* scores = (float*)(ws + SC_OFF);
    float* stats  = (float*)(ws + ST_OFF);
    float* ctxp   = (float*)(ws + CP_OFF);

    float* out_ctx   = (float*)d_out;
    float* out_alpha = out_ctx + 32 * 512;

    hipFuncSetAttribute((const void*)scores_kernel,
                        hipFuncAttributeMaxDynamicSharedMemorySize, SMEM_S);

    hipLaunchKernelGGL(wft_kernel, dim3(32), dim3(256), 0, stream, Wf, WfTi);
    hipLaunchKernelGGL(hb_kernel, dim3(32), dim3(256), 0, stream, hidden, Wh, bh, bfv, hb);
    hipLaunchKernelGGL(scores_kernel, dim3(4096), dim3(512), SMEM_S, stream,
                       feats, WfTi, hb, Ws, scores, stats);
    hipLaunchKernelGGL(ctx_kernel, dim3(4096), dim3(256), 0, stream,
                       feats, scores, stats, ctxp);
    hipLaunchKernelGGL(combine_kernel, dim3(32), dim3(256), 0, stream,
                       scores, stats, ctxp, out_ctx, out_alpha);
}